// Round 3
// baseline (611.949 us; speedup 1.0000x reference)
//
#include <hip/hip_runtime.h>

#define LATENT 40
#define NUM_FLOWS 30
#define PF 4  // prefetch depth (iterations of w/u held in registers)

typedef float f32x4 __attribute__((ext_vector_type(4)));

// 8 lanes per batch element. Lane idx (0..7) owns latent components
// [4*idx, 4*idx+4) (float4) plus component 32+idx (scalar) -> 40 total.
// Dot products reduce across the 8-lane group with __shfl_xor (masks 1,2,4).
// z stays in registers across all 30 flows. Depth-PF rotating prefetch keeps
// PF iterations of loads in flight.
//
// R3 vs R2 (failed absmax 1.375 on sum_ladj):
//  - tanh REVERTED to libm tanhf: its error feeds ladj via log|1+(1-t^2)s_wu|
//    which has 1/det amplification near singular flows -> needs <=1 ulp t.
//  - logf stays native __logf (v_log_f32): log's own error is NOT amplified
//    (absolute error ~ulp of result, ~1e-6), safe; saves ~30 libm instrs.
//  - nontemporal loads/stores kept on single-use streams (w,u,z,out).
__global__ __launch_bounds__(256) void nf_kernel(
    const float* __restrict__ z_k,   // [B, 40]
    const float* __restrict__ w,     // [B, 1200]
    const float* __restrict__ u,     // [B, 1200]
    const float* __restrict__ bias,  // [B, 30]
    float* __restrict__ out,         // [B*40] z_out then [B] sum_ladj
    int B)
{
    int tid  = blockIdx.x * 256 + threadIdx.x;
    int elem = tid >> 3;
    int idx  = tid & 7;
    if (elem >= B) return;

    const float* zrow = z_k + (size_t)elem * LATENT;
    f32x4 zA = __builtin_nontemporal_load((const f32x4*)(zrow + 4 * idx));
    float zt = __builtin_nontemporal_load(zrow + 32 + idx);

    const float* wrow = w + (size_t)elem * (NUM_FLOWS * LATENT);
    const float* urow = u + (size_t)elem * (NUM_FLOWS * LATENT);

    // Preload all 30 b values for this element: lane idx holds b[4idx..4idx+4)
    // (lane 7 holds only b[28],b[29]). Scalar loads, bounds-guarded tail.
    const float* brow = bias + (size_t)elem * NUM_FLOWS;
    float bv0 = 0.f, bv1 = 0.f, bv2 = 0.f, bv3 = 0.f;
    {
        int base = 4 * idx;
        bv0 = brow[base];
        bv1 = brow[base + 1];                        // base+1 <= 29, always valid
        if (base + 2 < NUM_FLOWS) bv2 = brow[base + 2];
        if (base + 3 < NUM_FLOWS) bv3 = brow[base + 3];
    }

    // Rotating prefetch buffers (become registers after full unroll).
    f32x4 wAb[PF], uAb[PF];
    float wtb[PF], utb[PF];
    #pragma unroll
    for (int i = 0; i < PF; ++i) {
        const float* wp = wrow + i * LATENT;
        const float* up = urow + i * LATENT;
        wAb[i] = __builtin_nontemporal_load((const f32x4*)(wp + 4 * idx));
        wtb[i] = __builtin_nontemporal_load(wp + 32 + idx);
        uAb[i] = __builtin_nontemporal_load((const f32x4*)(up + 4 * idx));
        utb[i] = __builtin_nontemporal_load(up + 32 + idx);
    }

    float ladj = 0.f;

    #pragma unroll
    for (int i = 0; i < NUM_FLOWS; ++i) {
        const int s = i % PF;  // compile-time constant after unroll
        f32x4 wA = wAb[s];  float wt = wtb[s];
        f32x4 uA = uAb[s];  float ut = utb[s];

        if (i + PF < NUM_FLOWS) {
            const float* wp = wrow + (i + PF) * LATENT;
            const float* up = urow + (i + PF) * LATENT;
            wAb[s] = __builtin_nontemporal_load((const f32x4*)(wp + 4 * idx));
            wtb[s] = __builtin_nontemporal_load(wp + 32 + idx);
            uAb[s] = __builtin_nontemporal_load((const f32x4*)(up + 4 * idx));
            utb[s] = __builtin_nontemporal_load(up + 32 + idx);
        }

        float s_wz = wA.x * zA.x + wA.y * zA.y + wA.z * zA.z + wA.w * zA.w + wt * zt;
        float s_wu = wA.x * uA.x + wA.y * uA.y + wA.z * uA.z + wA.w * uA.w + wt * ut;

        // Fold b_i in pre-reduction: exactly the owner lane (idx == i>>2) adds
        // component (i&3); after the xor-reduce all 8 lanes hold sum(w.z)+b_i.
        if (idx == (i >> 2)) {
            const int c = i & 3;
            s_wz += (c == 0) ? bv0 : (c == 1) ? bv1 : (c == 2) ? bv2 : bv3;
        }

        s_wz += __shfl_xor(s_wz, 1); s_wu += __shfl_xor(s_wu, 1);
        s_wz += __shfl_xor(s_wz, 2); s_wu += __shfl_xor(s_wu, 2);
        s_wz += __shfl_xor(s_wz, 4); s_wu += __shfl_xor(s_wu, 4);

        // Precision-critical: t feeds ladj through 1/det amplification near
        // singular flows -> must match libm tanhf (<=1 ulp). Do NOT fast-path.
        float t = tanhf(s_wz);

        zA.x += uA.x * t; zA.y += uA.y * t; zA.z += uA.z * t; zA.w += uA.w * t;
        zt   += ut * t;

        // sum(psi * u) = (1 - t^2) * sum(w * u)
        float det = fmaf(1.0f - t * t, s_wu, 1.0f);
        ladj += __logf(fabsf(det));   // native v_log_f32: error not amplified
    }

    float* zout = out + (size_t)elem * LATENT;
    __builtin_nontemporal_store(zA, (f32x4*)(zout + 4 * idx));
    __builtin_nontemporal_store(zt, zout + 32 + idx);
    if (idx == 0) __builtin_nontemporal_store(ladj, out + (size_t)B * LATENT + elem);
}

extern "C" void kernel_launch(void* const* d_in, const int* in_sizes, int n_in,
                              void* d_out, int out_size, void* d_ws, size_t ws_size,
                              hipStream_t stream) {
    const float* z_k  = (const float*)d_in[0];
    const float* w    = (const float*)d_in[1];
    const float* u    = (const float*)d_in[2];
    const float* bias = (const float*)d_in[3];
    float* out = (float*)d_out;

    int B = in_sizes[0] / LATENT;           // 65536
    int threads = B * 8;                    // 8 lanes per batch element
    int block = 256;
    int grid = (threads + block - 1) / block;
    nf_kernel<<<grid, block, 0, stream>>>(z_k, w, u, bias, out, B);
}